// Round 9
// baseline (243.903 us; speedup 1.0000x reference)
//
#include <hip/hip_runtime.h>

#define IN_F 1024
#define ASS 100000
#define OUT_F 1024
#define TOTAL (IN_F + ASS + OUT_F)  // 102048
#define ASS0 IN_F
#define OUT0 (IN_F + ASS)
#define NDST (ASS + OUT_F)  // 101024 destinations, node = ASS0 + d
#define NUM_ROUNDS 24

#define BIN_SZ 256  // dst nodes per bin (8 bits of payload)
#define NBINS ((NDST + BIN_SZ - 1) / BIN_SZ)  // 395
#define NCON 512    // construction blocks (2 blocks/CU with 1024 thr)
#define CON_T 1024  // construction threads per block
#define KR_T 1024   // kR threads per block (16 waves per bin)

typedef int i4v __attribute__((ext_vector_type(4)));
typedef float f4v __attribute__((ext_vector_type(4)));
typedef unsigned int u2v __attribute__((ext_vector_type(2)));

// ---------------------------------------------------------------------------
// Each assoc neuron fires exactly once at BFS level L(u).
// ltv[node] = {lev (u32), tv = tanh snapshot at fire time (f32)} packed 8B:
// one random gather per edge instead of two.
// Edge storage split: ua[e] = src<<8|dstoff (always streamed, 4B/edge),
// wcsr[e] = weight (4B, loaded only for active edges).
// Round r: one 1024-thread block owns each 256-dst bin exclusively; active
// edges (ltv[src].lev==r) accumulate tv*w into an LDS slice; epilogue applies
// first-receipt semantics. Empty rounds no-op via flags[r]. No cross-block
// merges or fences; all inter-round comms via kernel boundaries.
// Torn-8B-read safety: ltv writes only transition lev 255->r+1, so a reader
// checking lev==r can never pair a stale tv with a matching lev.
// ---------------------------------------------------------------------------

__global__ __launch_bounds__(256) void kz(float* mem, u2v* ltv, int* flags,
                                          int* bin_count) {
  int i = blockIdx.x * 256 + threadIdx.x;
  int gs = gridDim.x * 256;
  u2v init;
  init.x = 255u;
  init.y = 0u;
  for (int k = i; k < TOTAL; k += gs) {
    mem[k] = 0.f;
    ltv[k] = init;
  }
  for (int k = i; k < NBINS; k += gs) bin_count[k] = 0;
  if (i < 32) flags[i] = 0;
}

__global__ __launch_bounds__(256) void ki(const float* __restrict__ x,
                                          const float* __restrict__ iw,
                                          const int* __restrict__ ies,
                                          const int* __restrict__ ied, int E_in,
                                          float* mem, unsigned int* ltv_raw) {
  int e = blockIdx.x * 256 + threadIdx.x;
  if (e < E_in) {
    int d = ied[e];
    atomicAdd(&mem[d], x[ies[e]] * iw[e]);
    ltv_raw[2 * d] = 0u;  // lev = 0; benign race, all writers store 0
  }
}

// snapshot level-0 frontier: tv = tanh(mem), mem = 0
__global__ __launch_bounds__(256) void kp(float* mem, u2v* ltv) {
  int i = blockIdx.x * 256 + threadIdx.x;
  if (i < ASS) {
    int node = ASS0 + i;
    u2v lt = ltv[node];
    if (lt.x == 0u) {
      lt.y = __float_as_uint(tanhf(mem[node]));
      ltv[node] = lt;
      mem[node] = 0.f;
    }
  }
}

// per-block histogram -> h_all[bin*NCON + block]; totals -> bin_count
// cacheable loads: aed stays in L3 for kc's re-read
__global__ __launch_bounds__(CON_T) void kh(const int* __restrict__ aed,
                                            int E_a, int* h_all,
                                            int* bin_count) {
  __shared__ int h[NBINS];
  for (int b = threadIdx.x; b < NBINS; b += CON_T) h[b] = 0;
  __syncthreads();
  const i4v* aed4 = (const i4v*)aed;
  int nv4 = E_a >> 2;
  int stride = gridDim.x * CON_T;
  for (int v = blockIdx.x * CON_T + (int)threadIdx.x; v < nv4; v += stride) {
    i4v d4 = aed4[v];
    atomicAdd(&h[(d4.x - ASS0) >> 8], 1);
    atomicAdd(&h[(d4.y - ASS0) >> 8], 1);
    atomicAdd(&h[(d4.z - ASS0) >> 8], 1);
    atomicAdd(&h[(d4.w - ASS0) >> 8], 1);
  }
  if (blockIdx.x == 0) {
    for (int e = (nv4 << 2) + (int)threadIdx.x; e < E_a; e += CON_T)
      atomicAdd(&h[(aed[e] - ASS0) >> 8], 1);
  }
  __syncthreads();
  for (int b = threadIdx.x; b < NBINS; b += CON_T) {
    int c = h[b];
    h_all[b * NCON + blockIdx.x] = c;
    if (c) atomicAdd(&bin_count[b], c);
  }
}

// exclusive scan of bin counts (single block)
__global__ __launch_bounds__(256) void ks(const int* __restrict__ bin_count,
                                          int* bin_start) {
  __shared__ int sb[1024];
  __shared__ int sp[256];
  int tid = threadIdx.x;
  for (int k = 0; k < 4; ++k) {
    int t = tid + k * 256;
    sb[t] = (t < NBINS) ? bin_count[t] : 0;
  }
  __syncthreads();
  int i0 = tid * 4;
  int s = sb[i0] + sb[i0 + 1] + sb[i0 + 2] + sb[i0 + 3];
  sp[tid] = s;
  __syncthreads();
  for (int off = 1; off < 256; off <<= 1) {
    int v = (tid >= off) ? sp[tid - off] : 0;
    __syncthreads();
    sp[tid] += v;
    __syncthreads();
  }
  int run = (tid > 0) ? sp[tid - 1] : 0;
  for (int j = 0; j < 4; ++j) {
    int t = i0 + j;
    if (t < NBINS) bin_start[t] = run;
    run += sb[t];
  }
  if (tid == 255) bin_start[NBINS] = sp[255];
}

// per-bin column scan over NCON=512 block columns
__global__ __launch_bounds__(512) void ks2(const int* __restrict__ bin_start,
                                           int* h_all) {
  __shared__ int sp[512];
  int b = blockIdx.x;
  int tid = threadIdx.x;
  int v = h_all[b * NCON + tid];
  sp[tid] = v;
  __syncthreads();
  for (int off = 1; off < 512; off <<= 1) {
    int t = (tid >= off) ? sp[tid - off] : 0;
    __syncthreads();
    sp[tid] += t;
    __syncthreads();
  }
  h_all[b * NCON + tid] = bin_start[b] + sp[tid] - v;  // exclusive
}

// single-pass scatter with exact precomputed per-(block,bin) bases
__global__ __launch_bounds__(CON_T) void kc(const int* __restrict__ aes,
                                            const int* __restrict__ aed,
                                            const float* __restrict__ aw,
                                            int E_a,
                                            const int* __restrict__ h_all,
                                            unsigned* __restrict__ ua,
                                            float* __restrict__ wcsr) {
  __shared__ int cur[NBINS];
  for (int b = threadIdx.x; b < NBINS; b += CON_T)
    cur[b] = h_all[b * NCON + blockIdx.x];
  __syncthreads();
  const i4v* aed4 = (const i4v*)aed;
  const i4v* aes4 = (const i4v*)aes;
  const f4v* aw4 = (const f4v*)aw;
  int nv4 = E_a >> 2;
  int stride = gridDim.x * CON_T;
  for (int v = blockIdx.x * CON_T + (int)threadIdx.x; v < nv4; v += stride) {
    i4v d4 = aed4[v];  // L3-hot from kh
    i4v s4 = __builtin_nontemporal_load(&aes4[v]);
    f4v w4 = __builtin_nontemporal_load(&aw4[v]);
#pragma unroll
    for (int j = 0; j < 4; ++j) {
      int d = d4[j] - ASS0;
      int pos = atomicAdd(&cur[d >> 8], 1);
      ua[pos] = ((unsigned)s4[j] << 8) | (unsigned)(d & 255);
      wcsr[pos] = w4[j];
    }
  }
  if (blockIdx.x == 0) {
    for (int e = (nv4 << 2) + (int)threadIdx.x; e < E_a; e += CON_T) {
      int d = aed[e] - ASS0;
      int pos = atomicAdd(&cur[d >> 8], 1);
      ua[pos] = ((unsigned)aes[e] << 8) | (unsigned)(d & 255);
      wcsr[pos] = aw[e];
    }
  }
}

// one propagation round; grid = NBINS blocks x 1024 threads; no merges
__global__ __launch_bounds__(KR_T) void kR(int r, int* flags,
                                           const int* __restrict__ bin_start,
                                           const unsigned* __restrict__ ua,
                                           const float* __restrict__ wcsr,
                                           float* __restrict__ mem,
                                           u2v* __restrict__ ltv) {
  if (r > 0 && flags[r] == 0) return;  // uniform: empty round is a no-op
  __shared__ float slice[BIN_SZ];
  __shared__ int smask[BIN_SZ];
  __shared__ int newfront;
  int tid = threadIdx.x;
  int bin = blockIdx.x;
  if (tid < BIN_SZ) {
    slice[tid] = 0.f;
    smask[tid] = 0;
  }
  if (tid == 0) newfront = 0;
  __syncthreads();
  int e0 = bin_start[bin], e1 = bin_start[bin + 1];
  unsigned rl = (unsigned)r;
  for (int e = e0 + tid; e < e1; e += KR_T) {
    unsigned q = ua[e];   // coalesced 4B stream
    u2v lt = ltv[q >> 8]; // single 8B gather: {lev, tv}
    if (lt.x == rl) {
      atomicAdd(&slice[q & 255], __uint_as_float(lt.y) * wcsr[e]);
      smask[q & 255] = 1;
    }
  }
  __syncthreads();
  if (tid < BIN_SZ) {
    int d = bin * BIN_SZ + tid;
    if (d < NDST && smask[tid]) {
      int node = ASS0 + d;
      float nv = mem[node] + slice[tid];
      u2v lt = ltv[node];  // only this block ever writes this node's ltv
      if (lt.x == 255u) {  // first receipt: becomes working, fires next round
        u2v nl;
        nl.x = (unsigned)(r + 1);
        if (node < OUT0) {
          nl.y = __float_as_uint(tanhf(nv));  // snapshot at fire time
          ltv[node] = nl;
          mem[node] = 0.f;  // fired neurons erase memory
          newfront = 1;     // benign LDS race
        } else {
          nl.y = 0u;
          ltv[node] = nl;
          mem[node] = nv;  // outputs never fire, just accumulate
        }
      } else {
        mem[node] = nv;  // already fired/working: keep accumulating
      }
    }
  }
  __syncthreads();
  if (tid == 0 && newfront) flags[r + 1] = 1;
}

__global__ __launch_bounds__(256) void ko(const float* __restrict__ mem,
                                          float* __restrict__ out) {
  int i = blockIdx.x * 256 + threadIdx.x;
  if (i < OUT_F) out[i] = tanhf(mem[OUT0 + i]);
}

// ---------------------------------------------------------------------------
// Fallback dense multi-kernel path if ws too small.
// ---------------------------------------------------------------------------

__global__ __launch_bounds__(256) void k_init(float* mem, float* delta,
                                              int* status, int* got) {
  int i = blockIdx.x * 256 + threadIdx.x;
  if (i < TOTAL) {
    mem[i] = 0.f;
    delta[i] = 0.f;
    status[i] = 0;
    got[i] = 0;
  }
}
__global__ __launch_bounds__(256) void k_input(const float* __restrict__ x,
                                               const float* __restrict__ w,
                                               const int* __restrict__ src,
                                               const int* __restrict__ dst,
                                               int n, float* mem, int* got) {
  for (int e = blockIdx.x * 256 + threadIdx.x; e < n; e += gridDim.x * 256) {
    atomicAdd(&mem[dst[e]], x[src[e]] * w[e]);
    got[dst[e]] = 1;
  }
}
__global__ __launch_bounds__(256) void k_status0(int* status, int* got) {
  int i = blockIdx.x * 256 + threadIdx.x;
  if (i < TOTAL) {
    status[i] = got[i] ? 1 : 0;
    got[i] = 0;
  }
}
__global__ __launch_bounds__(256) void k_edge(const float* __restrict__ w,
                                              const int* __restrict__ src,
                                              const int* __restrict__ dst,
                                              int n,
                                              const float* __restrict__ mem,
                                              const int* __restrict__ status,
                                              float* delta, int* got) {
  for (int e = blockIdx.x * 256 + threadIdx.x; e < n; e += gridDim.x * 256) {
    int s = src[e];
    if (status[s] == 1) {
      atomicAdd(&delta[dst[e]], tanhf(mem[s]) * w[e]);
      got[dst[e]] = 1;
    }
  }
}
__global__ __launch_bounds__(256) void k_update(float* mem, float* delta,
                                                int* status, int* got) {
  int i = blockIdx.x * 256 + threadIdx.x;
  if (i < TOTAL) {
    int st = status[i];
    bool fire = (st == 1) && (i >= ASS0) && (i < OUT0);
    float d = delta[i];
    mem[i] = fire ? d : (mem[i] + d);
    status[i] = fire ? 2 : ((got[i] && st == 0) ? 1 : st);
    delta[i] = 0.f;
    got[i] = 0;
  }
}

extern "C" void kernel_launch(void* const* d_in, const int* in_sizes, int n_in,
                              void* d_out, int out_size, void* d_ws,
                              size_t ws_size, hipStream_t stream) {
  const float* x = (const float*)d_in[0];
  const float* iw = (const float*)d_in[1];
  const float* aw = (const float*)d_in[2];
  const int* ies = (const int*)d_in[3];
  const int* ied = (const int*)d_in[4];
  const int* aes = (const int*)d_in[5];
  const int* aed = (const int*)d_in[6];
  int E_in = in_sizes[1];
  int E_a = in_sizes[2];
  float* out = (float*)d_out;
  char* ws = (char*)d_ws;

  // layout (8B-aligned first): ua | wcsr | ltv | mem | h_all | bin_count |
  //   bin_start | flags
  size_t off_ua = 0;
  size_t off_w = off_ua + (size_t)E_a * 4;
  size_t off_ltv = ((off_w + (size_t)E_a * 4) + 7) & ~(size_t)7;
  size_t off_mem = off_ltv + (size_t)TOTAL * 8;
  size_t off_hall = off_mem + (size_t)TOTAL * 4;
  size_t off_bcnt = off_hall + (size_t)NBINS * NCON * 4;
  size_t off_bst = off_bcnt + (size_t)NBINS * 4;
  size_t off_flags = off_bst + (size_t)(NBINS + 1) * 4;
  size_t need = off_flags + 32 * 4;

  if (ws_size >= need) {
    unsigned* ua = (unsigned*)(ws + off_ua);
    float* wcsr = (float*)(ws + off_w);
    u2v* ltv = (u2v*)(ws + off_ltv);
    float* mem = (float*)(ws + off_mem);
    int* h_all = (int*)(ws + off_hall);
    int* bin_count = (int*)(ws + off_bcnt);
    int* bin_start = (int*)(ws + off_bst);
    int* flags = (int*)(ws + off_flags);

    kz<<<(TOTAL + 255) / 256, 256, 0, stream>>>(mem, ltv, flags, bin_count);
    ki<<<(E_in + 255) / 256, 256, 0, stream>>>(x, iw, ies, ied, E_in, mem,
                                               (unsigned int*)ltv);
    kp<<<(ASS + 255) / 256, 256, 0, stream>>>(mem, ltv);
    kh<<<NCON, CON_T, 0, stream>>>(aed, E_a, h_all, bin_count);
    ks<<<1, 256, 0, stream>>>(bin_count, bin_start);
    ks2<<<NBINS, 512, 0, stream>>>(bin_start, h_all);
    kc<<<NCON, CON_T, 0, stream>>>(aes, aed, aw, E_a, h_all, ua, wcsr);

    for (int r = 0; r < NUM_ROUNDS; ++r)
      kR<<<NBINS, KR_T, 0, stream>>>(r, flags, bin_start, ua, wcsr, mem, ltv);

    ko<<<(OUT_F + 255) / 256, 256, 0, stream>>>(mem, out);
    return;
  }

  // fallback: dense path
  float* mem = (float*)ws;
  float* delta = mem + TOTAL;
  int* status = (int*)(delta + TOTAL);
  int* got = status + TOTAL;
  const int nodeBlocks = (TOTAL + 255) / 256;
  k_init<<<nodeBlocks, 256, 0, stream>>>(mem, delta, status, got);
  int inBlocks = (E_in + 255) / 256;
  if (inBlocks > 1024) inBlocks = 1024;
  k_input<<<inBlocks, 256, 0, stream>>>(x, iw, ies, ied, E_in, mem, got);
  k_status0<<<nodeBlocks, 256, 0, stream>>>(status, got);
  int eBlocks = (E_a + 255) / 256;
  if (eBlocks > 2048) eBlocks = 2048;
  for (int r = 0; r < NUM_ROUNDS; ++r) {
    k_edge<<<eBlocks, 256, 0, stream>>>(aw, aes, aed, E_a, mem, status, delta,
                                        got);
    k_update<<<nodeBlocks, 256, 0, stream>>>(mem, delta, status, got);
  }
  ko<<<(OUT_F + 255) / 256, 256, 0, stream>>>(mem, out);
}

// Round 10
// 196.383 us; speedup vs baseline: 1.2420x; 1.2420x over previous
//
#include <hip/hip_runtime.h>

#define IN_F 1024
#define ASS 100000
#define OUT_F 1024
#define TOTAL (IN_F + ASS + OUT_F)  // 102048
#define ASS0 IN_F
#define OUT0 (IN_F + ASS)
#define NDST (ASS + OUT_F)  // 101024 destinations, node = ASS0 + d
#define NUM_ROUNDS 24

#define BIN_SZ 256  // dst nodes per bin (8 bits of payload)
#define NBINS ((NDST + BIN_SZ - 1) / BIN_SZ)  // 395
#define NCON 512    // construction blocks (2 blocks/CU with 1024 thr)
#define CON_T 1024  // construction threads per block
#define KR_T 1024   // kR threads per block (16 waves per bin)

typedef int i4v __attribute__((ext_vector_type(4)));
typedef float f4v __attribute__((ext_vector_type(4)));
typedef unsigned int u2v __attribute__((ext_vector_type(2)));

// ---------------------------------------------------------------------------
// Each assoc neuron fires exactly once at BFS level L(u).
// csr[e] = {src<<8 | dstoff, w} packed 8B: ONE coalesced stream load gives
// both the activity key and the weight; ONE 8B scattered store in kc.
// ltv[node] = {lev (u32), tv = tanh snapshot at fire time (f32)} packed 8B:
// one random gather per edge instead of two.
// Round r: one 1024-thread block owns each 256-dst bin exclusively; active
// edges (ltv[src].lev==r) accumulate tv*w into an LDS slice; epilogue applies
// first-receipt semantics. Empty rounds no-op via flags[r]. No cross-block
// merges or fences; all inter-round comms via kernel boundaries.
// Torn-8B-read safety: ltv writes only transition lev 255->r+1, so a reader
// checking lev==r can never pair a stale tv with a matching lev.
// ---------------------------------------------------------------------------

__global__ __launch_bounds__(256) void kz(float* mem, u2v* ltv, int* flags,
                                          int* bin_count) {
  int i = blockIdx.x * 256 + threadIdx.x;
  int gs = gridDim.x * 256;
  u2v init;
  init.x = 255u;
  init.y = 0u;
  for (int k = i; k < TOTAL; k += gs) {
    mem[k] = 0.f;
    ltv[k] = init;
  }
  for (int k = i; k < NBINS; k += gs) bin_count[k] = 0;
  if (i < 32) flags[i] = 0;
}

__global__ __launch_bounds__(256) void ki(const float* __restrict__ x,
                                          const float* __restrict__ iw,
                                          const int* __restrict__ ies,
                                          const int* __restrict__ ied, int E_in,
                                          float* mem, unsigned int* ltv_raw) {
  int e = blockIdx.x * 256 + threadIdx.x;
  if (e < E_in) {
    int d = ied[e];
    atomicAdd(&mem[d], x[ies[e]] * iw[e]);
    ltv_raw[2 * d] = 0u;  // lev = 0; benign race, all writers store 0
  }
}

// snapshot level-0 frontier: tv = tanh(mem), mem = 0
__global__ __launch_bounds__(256) void kp(float* mem, u2v* ltv) {
  int i = blockIdx.x * 256 + threadIdx.x;
  if (i < ASS) {
    int node = ASS0 + i;
    u2v lt = ltv[node];
    if (lt.x == 0u) {
      lt.y = __float_as_uint(tanhf(mem[node]));
      ltv[node] = lt;
      mem[node] = 0.f;
    }
  }
}

// per-block histogram -> h_all[bin*NCON + block]; totals -> bin_count
// cacheable loads: aed stays hot in L3 for kc's re-read
__global__ __launch_bounds__(CON_T) void kh(const int* __restrict__ aed,
                                            int E_a, int* h_all,
                                            int* bin_count) {
  __shared__ int h[NBINS];
  for (int b = threadIdx.x; b < NBINS; b += CON_T) h[b] = 0;
  __syncthreads();
  const i4v* aed4 = (const i4v*)aed;
  int nv4 = E_a >> 2;
  int stride = gridDim.x * CON_T;
  for (int v = blockIdx.x * CON_T + (int)threadIdx.x; v < nv4; v += stride) {
    i4v d4 = aed4[v];
    atomicAdd(&h[(d4.x - ASS0) >> 8], 1);
    atomicAdd(&h[(d4.y - ASS0) >> 8], 1);
    atomicAdd(&h[(d4.z - ASS0) >> 8], 1);
    atomicAdd(&h[(d4.w - ASS0) >> 8], 1);
  }
  if (blockIdx.x == 0) {
    for (int e = (nv4 << 2) + (int)threadIdx.x; e < E_a; e += CON_T)
      atomicAdd(&h[(aed[e] - ASS0) >> 8], 1);
  }
  __syncthreads();
  for (int b = threadIdx.x; b < NBINS; b += CON_T) {
    int c = h[b];
    h_all[b * NCON + blockIdx.x] = c;
    if (c) atomicAdd(&bin_count[b], c);
  }
}

// exclusive scan of bin counts (single block)
__global__ __launch_bounds__(256) void ks(const int* __restrict__ bin_count,
                                          int* bin_start) {
  __shared__ int sb[1024];
  __shared__ int sp[256];
  int tid = threadIdx.x;
  for (int k = 0; k < 4; ++k) {
    int t = tid + k * 256;
    sb[t] = (t < NBINS) ? bin_count[t] : 0;
  }
  __syncthreads();
  int i0 = tid * 4;
  int s = sb[i0] + sb[i0 + 1] + sb[i0 + 2] + sb[i0 + 3];
  sp[tid] = s;
  __syncthreads();
  for (int off = 1; off < 256; off <<= 1) {
    int v = (tid >= off) ? sp[tid - off] : 0;
    __syncthreads();
    sp[tid] += v;
    __syncthreads();
  }
  int run = (tid > 0) ? sp[tid - 1] : 0;
  for (int j = 0; j < 4; ++j) {
    int t = i0 + j;
    if (t < NBINS) bin_start[t] = run;
    run += sb[t];
  }
  if (tid == 255) bin_start[NBINS] = sp[255];
}

// per-bin column scan over NCON=512 block columns
__global__ __launch_bounds__(512) void ks2(const int* __restrict__ bin_start,
                                           int* h_all) {
  __shared__ int sp[512];
  int b = blockIdx.x;
  int tid = threadIdx.x;
  int v = h_all[b * NCON + tid];
  sp[tid] = v;
  __syncthreads();
  for (int off = 1; off < 512; off <<= 1) {
    int t = (tid >= off) ? sp[tid - off] : 0;
    __syncthreads();
    sp[tid] += t;
    __syncthreads();
  }
  h_all[b * NCON + tid] = bin_start[b] + sp[tid] - v;  // exclusive
}

// single-pass scatter with exact precomputed per-(block,bin) bases;
// ONE 8B store per edge
__global__ __launch_bounds__(CON_T) void kc(const int* __restrict__ aes,
                                            const int* __restrict__ aed,
                                            const float* __restrict__ aw,
                                            int E_a,
                                            const int* __restrict__ h_all,
                                            u2v* __restrict__ csr) {
  __shared__ int cur[NBINS];
  for (int b = threadIdx.x; b < NBINS; b += CON_T)
    cur[b] = h_all[b * NCON + blockIdx.x];
  __syncthreads();
  const i4v* aed4 = (const i4v*)aed;
  const i4v* aes4 = (const i4v*)aes;
  const f4v* aw4 = (const f4v*)aw;
  int nv4 = E_a >> 2;
  int stride = gridDim.x * CON_T;
  for (int v = blockIdx.x * CON_T + (int)threadIdx.x; v < nv4; v += stride) {
    i4v d4 = aed4[v];  // L3-hot from kh
    i4v s4 = __builtin_nontemporal_load(&aes4[v]);
    f4v w4 = __builtin_nontemporal_load(&aw4[v]);
#pragma unroll
    for (int j = 0; j < 4; ++j) {
      int d = d4[j] - ASS0;
      int pos = atomicAdd(&cur[d >> 8], 1);
      u2v q;
      q.x = ((unsigned)s4[j] << 8) | (unsigned)(d & 255);
      q.y = __float_as_uint(w4[j]);
      csr[pos] = q;
    }
  }
  if (blockIdx.x == 0) {
    for (int e = (nv4 << 2) + (int)threadIdx.x; e < E_a; e += CON_T) {
      int d = aed[e] - ASS0;
      int pos = atomicAdd(&cur[d >> 8], 1);
      u2v q;
      q.x = ((unsigned)aes[e] << 8) | (unsigned)(d & 255);
      q.y = __float_as_uint(aw[e]);
      csr[pos] = q;
    }
  }
}

// one propagation round; grid = NBINS blocks x 1024 threads; no merges
__global__ __launch_bounds__(KR_T) void kR(int r, int* flags,
                                           const int* __restrict__ bin_start,
                                           const u2v* __restrict__ csr,
                                           float* __restrict__ mem,
                                           u2v* __restrict__ ltv) {
  if (r > 0 && flags[r] == 0) return;  // uniform: empty round is a no-op
  __shared__ float slice[BIN_SZ];
  __shared__ int smask[BIN_SZ];
  __shared__ int newfront;
  int tid = threadIdx.x;
  int bin = blockIdx.x;
  if (tid < BIN_SZ) {
    slice[tid] = 0.f;
    smask[tid] = 0;
  }
  if (tid == 0) newfront = 0;
  __syncthreads();
  int e0 = bin_start[bin], e1 = bin_start[bin + 1];
  unsigned rl = (unsigned)r;
  for (int e = e0 + tid; e < e1; e += KR_T) {
    u2v q = __builtin_nontemporal_load(&csr[e]);  // 8B stream: key + w
    u2v lt = ltv[q.x >> 8];                       // 8B gather: {lev, tv}
    if (lt.x == rl) {
      atomicAdd(&slice[q.x & 255],
                __uint_as_float(lt.y) * __uint_as_float(q.y));
      smask[q.x & 255] = 1;
    }
  }
  __syncthreads();
  if (tid < BIN_SZ) {
    int d = bin * BIN_SZ + tid;
    if (d < NDST && smask[tid]) {
      int node = ASS0 + d;
      float nv = mem[node] + slice[tid];
      u2v lt = ltv[node];  // only this block ever writes this node's ltv
      if (lt.x == 255u) {  // first receipt: becomes working, fires next round
        u2v nl;
        nl.x = (unsigned)(r + 1);
        if (node < OUT0) {
          nl.y = __float_as_uint(tanhf(nv));  // snapshot at fire time
          ltv[node] = nl;
          mem[node] = 0.f;  // fired neurons erase memory
          newfront = 1;     // benign LDS race
        } else {
          nl.y = 0u;
          ltv[node] = nl;
          mem[node] = nv;  // outputs never fire, just accumulate
        }
      } else {
        mem[node] = nv;  // already fired/working: keep accumulating
      }
    }
  }
  __syncthreads();
  if (tid == 0 && newfront) flags[r + 1] = 1;
}

__global__ __launch_bounds__(256) void ko(const float* __restrict__ mem,
                                          float* __restrict__ out) {
  int i = blockIdx.x * 256 + threadIdx.x;
  if (i < OUT_F) out[i] = tanhf(mem[OUT0 + i]);
}

// ---------------------------------------------------------------------------
// Fallback dense multi-kernel path if ws too small.
// ---------------------------------------------------------------------------

__global__ __launch_bounds__(256) void k_init(float* mem, float* delta,
                                              int* status, int* got) {
  int i = blockIdx.x * 256 + threadIdx.x;
  if (i < TOTAL) {
    mem[i] = 0.f;
    delta[i] = 0.f;
    status[i] = 0;
    got[i] = 0;
  }
}
__global__ __launch_bounds__(256) void k_input(const float* __restrict__ x,
                                               const float* __restrict__ w,
                                               const int* __restrict__ src,
                                               const int* __restrict__ dst,
                                               int n, float* mem, int* got) {
  for (int e = blockIdx.x * 256 + threadIdx.x; e < n; e += gridDim.x * 256) {
    atomicAdd(&mem[dst[e]], x[src[e]] * w[e]);
    got[dst[e]] = 1;
  }
}
__global__ __launch_bounds__(256) void k_status0(int* status, int* got) {
  int i = blockIdx.x * 256 + threadIdx.x;
  if (i < TOTAL) {
    status[i] = got[i] ? 1 : 0;
    got[i] = 0;
  }
}
__global__ __launch_bounds__(256) void k_edge(const float* __restrict__ w,
                                              const int* __restrict__ src,
                                              const int* __restrict__ dst,
                                              int n,
                                              const float* __restrict__ mem,
                                              const int* __restrict__ status,
                                              float* delta, int* got) {
  for (int e = blockIdx.x * 256 + threadIdx.x; e < n; e += gridDim.x * 256) {
    int s = src[e];
    if (status[s] == 1) {
      atomicAdd(&delta[dst[e]], tanhf(mem[s]) * w[e]);
      got[dst[e]] = 1;
    }
  }
}
__global__ __launch_bounds__(256) void k_update(float* mem, float* delta,
                                                int* status, int* got) {
  int i = blockIdx.x * 256 + threadIdx.x;
  if (i < TOTAL) {
    int st = status[i];
    bool fire = (st == 1) && (i >= ASS0) && (i < OUT0);
    float d = delta[i];
    mem[i] = fire ? d : (mem[i] + d);
    status[i] = fire ? 2 : ((got[i] && st == 0) ? 1 : st);
    delta[i] = 0.f;
    got[i] = 0;
  }
}

extern "C" void kernel_launch(void* const* d_in, const int* in_sizes, int n_in,
                              void* d_out, int out_size, void* d_ws,
                              size_t ws_size, hipStream_t stream) {
  const float* x = (const float*)d_in[0];
  const float* iw = (const float*)d_in[1];
  const float* aw = (const float*)d_in[2];
  const int* ies = (const int*)d_in[3];
  const int* ied = (const int*)d_in[4];
  const int* aes = (const int*)d_in[5];
  const int* aed = (const int*)d_in[6];
  int E_in = in_sizes[1];
  int E_a = in_sizes[2];
  float* out = (float*)d_out;
  char* ws = (char*)d_ws;

  // layout (8B-aligned first): csr | ltv | mem | h_all | bin_count |
  //   bin_start | flags
  size_t off_csr = 0;
  size_t off_ltv = off_csr + (size_t)E_a * 8;
  size_t off_mem = off_ltv + (size_t)TOTAL * 8;
  size_t off_hall = off_mem + (size_t)TOTAL * 4;
  size_t off_bcnt = off_hall + (size_t)NBINS * NCON * 4;
  size_t off_bst = off_bcnt + (size_t)NBINS * 4;
  size_t off_flags = off_bst + (size_t)(NBINS + 1) * 4;
  size_t need = off_flags + 32 * 4;

  if (ws_size >= need) {
    u2v* csr = (u2v*)(ws + off_csr);
    u2v* ltv = (u2v*)(ws + off_ltv);
    float* mem = (float*)(ws + off_mem);
    int* h_all = (int*)(ws + off_hall);
    int* bin_count = (int*)(ws + off_bcnt);
    int* bin_start = (int*)(ws + off_bst);
    int* flags = (int*)(ws + off_flags);

    kz<<<(TOTAL + 255) / 256, 256, 0, stream>>>(mem, ltv, flags, bin_count);
    ki<<<(E_in + 255) / 256, 256, 0, stream>>>(x, iw, ies, ied, E_in, mem,
                                               (unsigned int*)ltv);
    kp<<<(ASS + 255) / 256, 256, 0, stream>>>(mem, ltv);
    kh<<<NCON, CON_T, 0, stream>>>(aed, E_a, h_all, bin_count);
    ks<<<1, 256, 0, stream>>>(bin_count, bin_start);
    ks2<<<NBINS, 512, 0, stream>>>(bin_start, h_all);
    kc<<<NCON, CON_T, 0, stream>>>(aes, aed, aw, E_a, h_all, csr);

    for (int r = 0; r < NUM_ROUNDS; ++r)
      kR<<<NBINS, KR_T, 0, stream>>>(r, flags, bin_start, csr, mem, ltv);

    ko<<<(OUT_F + 255) / 256, 256, 0, stream>>>(mem, out);
    return;
  }

  // fallback: dense path
  float* mem = (float*)ws;
  float* delta = mem + TOTAL;
  int* status = (int*)(delta + TOTAL);
  int* got = status + TOTAL;
  const int nodeBlocks = (TOTAL + 255) / 256;
  k_init<<<nodeBlocks, 256, 0, stream>>>(mem, delta, status, got);
  int inBlocks = (E_in + 255) / 256;
  if (inBlocks > 1024) inBlocks = 1024;
  k_input<<<inBlocks, 256, 0, stream>>>(x, iw, ies, ied, E_in, mem, got);
  k_status0<<<nodeBlocks, 256, 0, stream>>>(status, got);
  int eBlocks = (E_a + 255) / 256;
  if (eBlocks > 2048) eBlocks = 2048;
  for (int r = 0; r < NUM_ROUNDS; ++r) {
    k_edge<<<eBlocks, 256, 0, stream>>>(aw, aes, aed, E_a, mem, status, delta,
                                        got);
    k_update<<<nodeBlocks, 256, 0, stream>>>(mem, delta, status, got);
  }
  ko<<<(OUT_F + 255) / 256, 256, 0, stream>>>(mem, out);
}